// Round 7
// baseline (167.518 us; speedup 1.0000x reference)
//
#include <hip/hip_runtime.h>
#include <math.h>

#define BSZ 16
#define NQ 300
#define NT 50
#define K3 51
#define NPRED (BSZ*NQ)     // 4800
#define NTGT  (BSZ*NT)     // 800
#define NC    (NPRED*NTGT) // 3,840,000

// ---------------- DPP wave-min helpers (wave64, all lanes active) ----------------
template<int CTRL, int RMASK>
__device__ __forceinline__ double dpp_minstep_f64(double x) {
    long long bb = __double_as_longlong(x);
    int lo = (int)(bb & 0xFFFFFFFFll);
    int hi = (int)(bb >> 32);
    int mlo = __builtin_amdgcn_update_dpp(lo, lo, CTRL, RMASK, 0xF, false);
    int mhi = __builtin_amdgcn_update_dpp(hi, hi, CTRL, RMASK, 0xF, false);
    double other = __longlong_as_double(((long long)mhi << 32) | (long long)(unsigned)mlo);
    return fmin(x, other);
}
__device__ __forceinline__ double wave_min_f64(double x) {
    x = dpp_minstep_f64<0xB1, 0xF>(x);
    x = dpp_minstep_f64<0x4E, 0xF>(x);
    x = dpp_minstep_f64<0x141, 0xF>(x);
    x = dpp_minstep_f64<0x140, 0xF>(x);
    x = dpp_minstep_f64<0x142, 0xA>(x);   // lanes 16-31,48-63 <- lane 15/47
    x = dpp_minstep_f64<0x143, 0xC>(x);   // lanes 32-63 <- lane 31; lane 63 = global min
    long long bb = __double_as_longlong(x);
    int lo = __builtin_amdgcn_readlane((int)(bb & 0xFFFFFFFFll), 63);
    int hi = __builtin_amdgcn_readlane((int)(bb >> 32), 63);
    return __longlong_as_double(((long long)hi << 32) | (long long)(unsigned)lo);
}
template<int CTRL, int RMASK>
__device__ __forceinline__ float dpp_minstep_f32(float x) {
    int m = __builtin_amdgcn_update_dpp(__float_as_int(x), __float_as_int(x), CTRL, RMASK, 0xF, false);
    return fminf(x, __int_as_float(m));
}
__device__ __forceinline__ float wave_min_f32(float x) {
    x = dpp_minstep_f32<0xB1, 0xF>(x);
    x = dpp_minstep_f32<0x4E, 0xF>(x);
    x = dpp_minstep_f32<0x141, 0xF>(x);
    x = dpp_minstep_f32<0x140, 0xF>(x);
    x = dpp_minstep_f32<0x142, 0xA>(x);
    x = dpp_minstep_f32<0x143, 0xC>(x);
    return __int_as_float(__builtin_amdgcn_readlane(__float_as_int(x), 63));
}
__device__ __forceinline__ double readlane_f64(double x, int lane) {
    long long bb = __double_as_longlong(x);
    int lo = __builtin_amdgcn_readlane((int)(bb & 0xFFFFFFFFll), lane);
    int hi = __builtin_amdgcn_readlane((int)(bb >> 32), lane);
    return __longlong_as_double(((long long)hi << 32) | (long long)(unsigned)lo);
}

// Identical formula/op-order everywhere -> bitwise-identical cost values.
__device__ __forceinline__ float giou_cost(
    float plt0, float plt1, float plt2, float prb0, float prb1, float prb2, float pvol,
    float tlt0, float tlt1, float tlt2, float trb0, float trb1, float trb2, float tvol)
{
    float inter = fmaxf(fminf(prb0,trb0) - fmaxf(plt0,tlt0), 0.f);
    inter *= fmaxf(fminf(prb1,trb1) - fmaxf(plt1,tlt1), 0.f);
    inter *= fmaxf(fminf(prb2,trb2) - fmaxf(plt2,tlt2), 0.f);
    float evol = fmaxf(fmaxf(prb0,trb0) - fminf(plt0,tlt0), 0.f);
    evol *= fmaxf(fmaxf(prb1,trb1) - fminf(plt1,tlt1), 0.f);
    evol *= fmaxf(fmaxf(prb2,trb2) - fminf(plt2,tlt2), 0.f);
    float uni = pvol + tvol - inter;
    return inter/uni - (evol - uni)/evol;
}

// ================= kernel 1: cost matrix, LDS-staged coalesced writes =================
__global__ __launch_bounds__(1024) void cost_kernel(
    const float* __restrict__ pred_kp, const float* __restrict__ pred_boxes,
    const float* __restrict__ tgt_boxes, const float* __restrict__ tgt_kp,
    float* __restrict__ C)
{
    __shared__ __align__(16) float s_dk[80*56];   // padded dist_kp rows
    __shared__ float s_tbox[80*12];               // lt0-2, rb0-2, vol, pad, pad, s0-2
    __shared__ float s_pk[64*K3];
    __shared__ float s_out[64*81];                // stride 81: conflict-free scatter

    const int cb = blockIdx.x;
    const int pb = cb % 75, tb = cb / 75;
    const int p0 = pb * 64, t0 = tb * 80;
    const int tid = threadIdx.x;

    if (tid < 80) {
        const float* tb6 = tgt_boxes + (size_t)(t0 + tid) * 6;
        float c0=tb6[0], c1=tb6[1], c2=tb6[2], s0=tb6[3], s1=tb6[4], s2=tb6[5];
        float l0=c0-0.5f*s0, l1=c1-0.5f*s1, l2=c2-0.5f*s2;
        float r0=c0+0.5f*s0, r1=c1+0.5f*s1, r2=c2+0.5f*s2;
        float* tw = s_tbox + tid*12;
        tw[0]=l0; tw[1]=l1; tw[2]=l2; tw[3]=r0; tw[4]=r1; tw[5]=r2;
        tw[6]=(r0-l0)*(r1-l1)*(r2-l2);
        tw[9]=s0; tw[10]=s1; tw[11]=s2;
    }
    __syncthreads();
    for (int e = tid; e < 80*K3; e += 1024) {
        int t = e / K3; int c = e - t*K3; int d = c % 3;
        float kp = tgt_kp[(size_t)t0*K3 + e];
        s_dk[t*56 + c] = (kp - s_tbox[t*12 + d]) / s_tbox[t*12 + 9 + d];
    }
    for (int e = tid; e < 64*K3; e += 1024)
        s_pk[e] = pred_kp[(size_t)p0*K3 + e];
    __syncthreads();

    const int pl = tid & 63, g = tid >> 6;
    float a[K3];
    #pragma unroll
    for (int c = 0; c < K3; ++c) a[c] = s_pk[pl*K3 + c];
    const int p = p0 + pl;
    const float* pb6 = pred_boxes + (size_t)p * 6;
    float pc0=pb6[0],pc1=pb6[1],pc2=pb6[2],ps0=pb6[3],ps1=pb6[4],ps2=pb6[5];
    float plt0=pc0-0.5f*ps0, plt1=pc1-0.5f*ps1, plt2=pc2-0.5f*ps2;
    float prb0=pc0+0.5f*ps0, prb1=pc1+0.5f*ps1, prb2=pc2+0.5f*ps2;
    float pvol=(prb0-plt0)*(prb1-plt1)*(prb2-plt2);

    #pragma unroll
    for (int k = 0; k < 5; ++k) {
        int tl = g*5 + k;                       // wave-uniform -> broadcast LDS reads
        const float* bbp = s_dk + tl*56;
        float sum = 0.f;
        #pragma unroll
        for (int c4 = 0; c4 < 12; ++c4) {       // ascending c, serial adds (order fixed)
            float4 q = *(const float4*)(bbp + 4*c4);
            sum += fabsf(a[4*c4+0] - q.x);
            sum += fabsf(a[4*c4+1] - q.y);
            sum += fabsf(a[4*c4+2] - q.z);
            sum += fabsf(a[4*c4+3] - q.w);
        }
        sum += fabsf(a[48] - bbp[48]);
        sum += fabsf(a[49] - bbp[49]);
        sum += fabsf(a[50] - bbp[50]);
        const float* tw = s_tbox + tl*12;
        float g_ = giou_cost(plt0,plt1,plt2,prb0,prb1,prb2,pvol,
                             tw[0],tw[1],tw[2],tw[3],tw[4],tw[5],tw[6]);
        s_out[pl*81 + tl] = sum - g_;           // stride 81, tl wave-uniform -> conflict-free
    }
    __syncthreads();

    // coalesced write-out: lane dimension runs along t (256 B per wave instruction)
    for (int e = tid; e < 64*80; e += 1024) {
        int pp = e / 80, t = e - pp*80;
        C[(size_t)(p0+pp)*NTGT + (t0+t)] = s_out[pp*81 + t];
    }
}

// ================= kernel 2: register-tile JV LAP, one wave per batch =================
// Trajectory-exact replica of the reference _lap (cold duals, scipy order, np.argmin ties).
// Tile read straight from C (diagonal 50x300 block, transposed into per-lane registers).
__global__ __launch_bounds__(64, 1) void lap_kernel(const float* __restrict__ C,
                                                    float* __restrict__ out_idx)
{
    const int b  = blockIdx.x;
    const int ln = threadIdx.x;
    const float* gC = C + (size_t)(b*NQ)*NTGT + b*NT;   // row j (pred): gC[j*800 + r]

    // lane ln owns columns j = ln + 64*s (s=0..4); slot 4 invalid for ln>=44
    float t0_[NT], t1_[NT], t2_[NT], t3_[NT], t4_[NT];
    const int j4 = (ln < 44) ? (ln + 256) : 0;  // dummy row for invalid slot (value unused)
    #pragma unroll
    for (int r = 0; r < NT; ++r) {
        t0_[r] = gC[(size_t)(ln      )*NTGT + r];
        t1_[r] = gC[(size_t)(ln +  64)*NTGT + r];
        t2_[r] = gC[(size_t)(ln + 128)*NTGT + r];
        t3_[r] = gC[(size_t)(ln + 192)*NTGT + r];
        t4_[r] = gC[(size_t)(j4      )*NTGT + r];
    }

    const double DINF = __builtin_inf();
    double u = 0.0;                     // dual for row ln (ln<50)
    int c4r = -1;                       // col4row[ln]
    double v[5], sh[5];
    int pth[5];
    #pragma unroll
    for (int s = 0; s < 5; ++s) v[s] = 0.0;

#define ROWC(I) case I: cfa[0]=t0_[I]; cfa[1]=t1_[I]; cfa[2]=t2_[I]; cfa[3]=t3_[I]; cfa[4]=t4_[I]; break;

    for (int curRow = 0; curRow < NT; ++curRow) {
        #pragma unroll
        for (int s = 0; s < 5; ++s) { sh[s] = DINF; pth[s] = -1; }
        int SCm = (ln < 44) ? 0 : 0x10;            // invalid slot pre-closed
        unsigned long long SRmask = 0ull;
        int i = curRow;
        double minVal = 0.0;
        int sink = -1;

        while (true) {
            SRmask |= (1ull << i);
            float cfa[5];
            switch (i) {
                ROWC(0)  ROWC(1)  ROWC(2)  ROWC(3)  ROWC(4)  ROWC(5)  ROWC(6)  ROWC(7)
                ROWC(8)  ROWC(9)  ROWC(10) ROWC(11) ROWC(12) ROWC(13) ROWC(14) ROWC(15)
                ROWC(16) ROWC(17) ROWC(18) ROWC(19) ROWC(20) ROWC(21) ROWC(22) ROWC(23)
                ROWC(24) ROWC(25) ROWC(26) ROWC(27) ROWC(28) ROWC(29) ROWC(30) ROWC(31)
                ROWC(32) ROWC(33) ROWC(34) ROWC(35) ROWC(36) ROWC(37) ROWC(38) ROWC(39)
                ROWC(40) ROWC(41) ROWC(42) ROWC(43) ROWC(44) ROWC(45) ROWC(46) ROWC(47)
                ROWC(48) ROWC(49)
                default: cfa[0]=cfa[1]=cfa[2]=cfa[3]=cfa[4]=0.f; break;
            }
            double u_i = readlane_f64(u, i);       // i is wave-uniform -> v_readlane
            double lmin = DINF;
            #pragma unroll
            for (int s = 0; s < 5; ++s) {
                bool open = ((SCm >> s) & 1) == 0;
                double r = ((minVal + (double)cfa[s]) - u_i) - v[s];  // reference op order
                bool upd = open && (r < sh[s]);
                sh[s]  = upd ? r : sh[s];
                pth[s] = upd ? i : pth[s];
                lmin = fmin(lmin, open ? sh[s] : DINF);
            }
            // exact f64 min over open columns: f32 pre-reduce (monotone cast), exact fallback
            float k32 = (float)lmin;
            float m32 = wave_min_f32(k32);
            unsigned long long candm = __ballot(k32 == m32);
            double m;
            if (__popcll(candm) == 1) {
                m = readlane_f64(lmin, (int)__builtin_ctzll(candm));   // exact f64 min
            } else {
                m = wave_min_f64(lmin);                                // exact fallback
            }
            minVal = m;
            // argmin-j: first open column (ascending j = ln+64s) whose sh equals m
            unsigned long long b0 = __ballot((((SCm >> 0) & 1) == 0) && (sh[0] == m));
            unsigned long long b1 = __ballot((((SCm >> 1) & 1) == 0) && (sh[1] == m));
            unsigned long long b2 = __ballot((((SCm >> 2) & 1) == 0) && (sh[2] == m));
            unsigned long long b3 = __ballot((((SCm >> 3) & 1) == 0) && (sh[3] == m));
            unsigned long long b4 = __ballot((((SCm >> 4) & 1) == 0) && (sh[4] == m));
            int jstar;
            if      (b0) jstar =       __builtin_ctzll(b0);
            else if (b1) jstar =  64 + __builtin_ctzll(b1);
            else if (b2) jstar = 128 + __builtin_ctzll(b2);
            else if (b3) jstar = 192 + __builtin_ctzll(b3);
            else         jstar = 256 + __builtin_ctzll(b4);
            // close column jstar
            if (ln == (jstar & 63)) SCm |= 1 << (jstar >> 6);
            // row4col[jstar] via col4row ballot (col4row constant during Dijkstra)
            unsigned long long mm = __ballot((ln < NT) && (c4r == jstar));
            if (mm == 0ull) { sink = jstar; break; }
            i = __builtin_ctzll(mm);
        }

        // ---- dual updates (pre-augment col4row) ----
        int cg  = (c4r >= 0) ? c4r : 0;
        int gow = cg & 63, gsl = cg >> 6;
        double g0 = __shfl(sh[0], gow);
        double g1 = __shfl(sh[1], gow);
        double g2 = __shfl(sh[2], gow);
        double g3 = __shfl(sh[3], gow);
        double g4 = __shfl(sh[4], gow);
        double gg = g0;
        gg = (gsl == 1) ? g1 : gg;
        gg = (gsl == 2) ? g2 : gg;
        gg = (gsl == 3) ? g3 : gg;
        gg = (gsl == 4) ? g4 : gg;
        bool inSR = (ln < NT) && ((SRmask >> ln) & 1ull);
        double du = (ln == curRow) ? minVal : (minVal - gg);
        u = inSR ? (u + du) : u;
        #pragma unroll
        for (int s = 0; s < 5; ++s) {
            bool closed = ((SCm >> s) & 1) != 0;
            v[s] = closed ? (v[s] - (minVal - sh[s])) : v[s];
        }

        // ---- augment (uniform j/i chain -> readlane) ----
        int j = sink;
        while (true) {
            int ow2 = j & 63, sl2 = j >> 6;
            int ps = pth[0];
            ps = (sl2==1) ? pth[1] : ps;
            ps = (sl2==2) ? pth[2] : ps;
            ps = (sl2==3) ? pth[3] : ps;
            ps = (sl2==4) ? pth[4] : ps;
            int ii = __builtin_amdgcn_readlane(ps, ow2);   // path[j]
            int jj = __builtin_amdgcn_readlane(c4r, ii);   // old col4row[ii]
            if (ln == ii) c4r = j;                          // col4row[ii] = j
            j = jj;
            if (ii == curRow) break;
        }
    }

    // ---- emit indices (argsort of matched pred indices) ----
    __shared__ int smem_i[NT];
    if (ln < NT) smem_i[ln] = c4r;
    __syncthreads();
    int myc = c4r;
    int rank = 0;
    for (int s2 = 0; s2 < NT; ++s2) rank += (smem_i[s2] < myc) ? 1 : 0;
    if (ln < NT) {
        out_idx[b*(2*NT) + rank]      = (float)myc; // sorted pred (q) indices
        out_idx[b*(2*NT) + NT + rank] = (float)ln;  // matched tgt (t) indices
    }
}

extern "C" void kernel_launch(void* const* d_in, const int* in_sizes, int n_in,
                              void* d_out, int out_size, void* d_ws, size_t ws_size,
                              hipStream_t stream)
{
    const float* pred_kp    = (const float*)d_in[0];
    const float* pred_boxes = (const float*)d_in[1];
    const float* tgt_boxes  = (const float*)d_in[2];
    const float* tgt_kp     = (const float*)d_in[3];
    float* C   = (float*)d_out;
    float* idx = C + NC;

    cost_kernel<<<750, 1024, 0, stream>>>(pred_kp, pred_boxes, tgt_boxes, tgt_kp, C);
    lap_kernel<<<BSZ, 64, 0, stream>>>(C, idx);
}

// Round 8
// 152.922 us; speedup vs baseline: 1.0955x; 1.0955x over previous
//
#include <hip/hip_runtime.h>
#include <math.h>

#define BSZ 16
#define NQ 300
#define NT 50
#define K3 51
#define NPRED (BSZ*NQ)     // 4800
#define NTGT  (BSZ*NT)     // 800
#define NC    (NPRED*NTGT) // 3,840,000
#define TSTRIDE 301        // lap tile row stride (floats), odd -> conflict-free
#define SMEMF 15104        // floats: 50*301 tile + slack (60.4 KB)

// ---------------- DPP wave-min helpers (wave64, all lanes active) ----------------
template<int CTRL, int RMASK>
__device__ __forceinline__ double dpp_minstep_f64(double x) {
    long long bb = __double_as_longlong(x);
    int lo = (int)(bb & 0xFFFFFFFFll);
    int hi = (int)(bb >> 32);
    int mlo = __builtin_amdgcn_update_dpp(lo, lo, CTRL, RMASK, 0xF, false);
    int mhi = __builtin_amdgcn_update_dpp(hi, hi, CTRL, RMASK, 0xF, false);
    double other = __longlong_as_double(((long long)mhi << 32) | (long long)(unsigned)mlo);
    return fmin(x, other);
}
__device__ __forceinline__ double wave_min_f64(double x) {
    x = dpp_minstep_f64<0xB1, 0xF>(x);
    x = dpp_minstep_f64<0x4E, 0xF>(x);
    x = dpp_minstep_f64<0x141, 0xF>(x);
    x = dpp_minstep_f64<0x140, 0xF>(x);
    x = dpp_minstep_f64<0x142, 0xA>(x);   // lanes 16-31,48-63 <- lane 15/47
    x = dpp_minstep_f64<0x143, 0xC>(x);   // lanes 32-63 <- lane 31; lane 63 = global min
    long long bb = __double_as_longlong(x);
    int lo = __builtin_amdgcn_readlane((int)(bb & 0xFFFFFFFFll), 63);
    int hi = __builtin_amdgcn_readlane((int)(bb >> 32), 63);
    return __longlong_as_double(((long long)hi << 32) | (long long)(unsigned)lo);
}
template<int CTRL, int RMASK>
__device__ __forceinline__ float dpp_minstep_f32(float x) {
    int m = __builtin_amdgcn_update_dpp(__float_as_int(x), __float_as_int(x), CTRL, RMASK, 0xF, false);
    return fminf(x, __int_as_float(m));
}
__device__ __forceinline__ float wave_min_f32(float x) {
    x = dpp_minstep_f32<0xB1, 0xF>(x);
    x = dpp_minstep_f32<0x4E, 0xF>(x);
    x = dpp_minstep_f32<0x141, 0xF>(x);
    x = dpp_minstep_f32<0x140, 0xF>(x);
    x = dpp_minstep_f32<0x142, 0xA>(x);
    x = dpp_minstep_f32<0x143, 0xC>(x);
    return __int_as_float(__builtin_amdgcn_readlane(__float_as_int(x), 63));
}
__device__ __forceinline__ double readlane_f64(double x, int lane) {
    long long bb = __double_as_longlong(x);
    int lo = __builtin_amdgcn_readlane((int)(bb & 0xFFFFFFFFll), lane);
    int hi = __builtin_amdgcn_readlane((int)(bb >> 32), lane);
    return __longlong_as_double(((long long)hi << 32) | (long long)(unsigned)lo);
}

// Identical formula/op-order used by BOTH paths -> bitwise-identical cost values.
__device__ __forceinline__ float giou_cost(
    float plt0, float plt1, float plt2, float prb0, float prb1, float prb2, float pvol,
    float tlt0, float tlt1, float tlt2, float trb0, float trb1, float trb2, float tvol)
{
    float inter = fmaxf(fminf(prb0,trb0) - fmaxf(plt0,tlt0), 0.f);
    inter *= fmaxf(fminf(prb1,trb1) - fmaxf(plt1,tlt1), 0.f);
    inter *= fmaxf(fminf(prb2,trb2) - fmaxf(plt2,tlt2), 0.f);
    float evol = fmaxf(fmaxf(prb0,trb0) - fminf(plt0,tlt0), 0.f);
    evol *= fmaxf(fmaxf(prb1,trb1) - fminf(plt1,tlt1), 0.f);
    evol *= fmaxf(fmaxf(prb2,trb2) - fminf(plt2,tlt2), 0.f);
    float uni = pvol + tvol - inter;
    return inter/uni - (evol - uni)/evol;
}

__global__ __launch_bounds__(1024) void fused_kernel(
    const float* __restrict__ pred_kp, const float* __restrict__ pred_boxes,
    const float* __restrict__ tgt_boxes, const float* __restrict__ tgt_kp,
    float* __restrict__ C, float* __restrict__ out_idx)
{
    __shared__ __align__(16) float smem[SMEMF];
    const int bid = blockIdx.x;
    const int tid = threadIdx.x;

    if (bid >= BSZ) {
        // ================= cost-matrix path: 64 preds x 80 tgts per block =================
        const int cb = bid - BSZ;
        const int pb = cb % 75, tb = cb / 75;
        const int p0 = pb * 64, t0 = tb * 80;
        float* s_dk   = smem;            // 80 x 56 (padded, 16B-aligned rows)
        float* s_tbox = smem + 4480;     // 80 x 12: lt0-2, rb0-2, vol, pad, pad, s0-2
        float* s_pk   = smem + 5440;     // 64 x 51

        if (tid < 80) {
            const float* tb6 = tgt_boxes + (size_t)(t0 + tid) * 6;
            float c0=tb6[0], c1=tb6[1], c2=tb6[2], s0=tb6[3], s1=tb6[4], s2=tb6[5];
            float l0=c0-0.5f*s0, l1=c1-0.5f*s1, l2=c2-0.5f*s2;
            float r0=c0+0.5f*s0, r1=c1+0.5f*s1, r2=c2+0.5f*s2;
            float* tw = s_tbox + tid*12;
            tw[0]=l0; tw[1]=l1; tw[2]=l2; tw[3]=r0; tw[4]=r1; tw[5]=r2;
            tw[6]=(r0-l0)*(r1-l1)*(r2-l2);
            tw[9]=s0; tw[10]=s1; tw[11]=s2;
        }
        __syncthreads();
        for (int e = tid; e < 80*K3; e += 1024) {
            int t = e / K3; int c = e - t*K3; int d = c % 3;
            float kp = tgt_kp[(size_t)t0*K3 + e];
            s_dk[t*56 + c] = (kp - s_tbox[t*12 + d]) / s_tbox[t*12 + 9 + d];
        }
        for (int e = tid; e < 64*K3; e += 1024)
            s_pk[e] = pred_kp[(size_t)p0*K3 + e];
        __syncthreads();

        const int pl = tid & 63, g = tid >> 6;
        float a[K3];
        #pragma unroll
        for (int c = 0; c < K3; ++c) a[c] = s_pk[pl*K3 + c];
        const int p = p0 + pl;
        const float* pb6 = pred_boxes + (size_t)p * 6;
        float pc0=pb6[0],pc1=pb6[1],pc2=pb6[2],ps0=pb6[3],ps1=pb6[4],ps2=pb6[5];
        float plt0=pc0-0.5f*ps0, plt1=pc1-0.5f*ps1, plt2=pc2-0.5f*ps2;
        float prb0=pc0+0.5f*ps0, prb1=pc1+0.5f*ps1, prb2=pc2+0.5f*ps2;
        float pvol=(prb0-plt0)*(prb1-plt1)*(prb2-plt2);

        #pragma unroll
        for (int k = 0; k < 5; ++k) {
            int tl = g*5 + k;                       // wave-uniform -> broadcast LDS reads
            const float* bbp = s_dk + tl*56;
            float sum = 0.f;
            #pragma unroll
            for (int c4 = 0; c4 < 12; ++c4) {       // ascending c, serial adds (order fixed)
                float4 q = *(const float4*)(bbp + 4*c4);
                sum += fabsf(a[4*c4+0] - q.x);
                sum += fabsf(a[4*c4+1] - q.y);
                sum += fabsf(a[4*c4+2] - q.z);
                sum += fabsf(a[4*c4+3] - q.w);
            }
            sum += fabsf(a[48] - bbp[48]);
            sum += fabsf(a[49] - bbp[49]);
            sum += fabsf(a[50] - bbp[50]);
            const float* tw = s_tbox + tl*12;
            float g_ = giou_cost(plt0,plt1,plt2,prb0,prb1,prb2,pvol,
                                 tw[0],tw[1],tw[2],tw[3],tw[4],tw[5],tw[6]);
            C[(size_t)p*NTGT + (t0+tl)] = sum - g_;
        }
        return;
    }

    // ================= LAP path: one block per batch =================
    const int b = bid;
    const int ln = tid & 63, w = tid >> 6;
    const int bq0 = b*NQ, bt0 = b*NT;
    float* tile = smem;                 // becomes [50][301] cost tile

    // stage tgt_kp slice into (future) tile area
    for (int e = tid; e < NT*K3; e += 1024)
        tile[e] = tgt_kp[(size_t)bt0*K3 + e];
    __syncthreads();

    // per-lane target row -> registers (every wave redundantly; lanes 0..49)
    float dk[K3];
    float tl0=0,tl1=0,tl2=0,tr0=0,tr1=0,tr2=0,tvol=0;
    if (ln < NT) {
        const float* tb6 = tgt_boxes + (size_t)(bt0+ln)*6;
        float c0=tb6[0],c1=tb6[1],c2=tb6[2],s0=tb6[3],s1=tb6[4],s2=tb6[5];
        tl0=c0-0.5f*s0; tl1=c1-0.5f*s1; tl2=c2-0.5f*s2;
        tr0=c0+0.5f*s0; tr1=c1+0.5f*s1; tr2=c2+0.5f*s2;
        tvol=(tr0-tl0)*(tr1-tl1)*(tr2-tl2);
        #pragma unroll
        for (int c = 0; c < K3; ++c) {
            int d = c % 3;
            float L = (d==0)?tl0:((d==1)?tl1:tl2);
            float S = (d==0)?s0:((d==1)?s1:s2);
            dk[c] = (tile[ln*K3 + c] - L) / S;
        }
    }
    __syncthreads();

    // build cost tile: wave w handles preds p = w, w+16, ... (bitwise same math as C path)
    for (int p = w; p < NQ; p += 16) {
        const float* prow = pred_kp + (size_t)(bq0+p)*K3;
        const float* pb6  = pred_boxes + (size_t)(bq0+p)*6;
        float pc0=pb6[0],pc1=pb6[1],pc2=pb6[2],ps0=pb6[3],ps1=pb6[4],ps2=pb6[5];
        float plt0=pc0-0.5f*ps0, plt1=pc1-0.5f*ps1, plt2=pc2-0.5f*ps2;
        float prb0=pc0+0.5f*ps0, prb1=pc1+0.5f*ps1, prb2=pc2+0.5f*ps2;
        float pvol=(prb0-plt0)*(prb1-plt1)*(prb2-plt2);
        if (ln < NT) {
            float sum = 0.f;
            #pragma unroll
            for (int c = 0; c < K3; ++c) sum += fabsf(prow[c] - dk[c]);
            float g_ = giou_cost(plt0,plt1,plt2,prb0,prb1,prb2,pvol,
                                 tl0,tl1,tl2,tr0,tr1,tr2,tvol);
            tile[ln*TSTRIDE + p] = sum - g_;
        }
    }
    __syncthreads();
    if (w != 0) return;                 // wave 0 continues alone; no more s_barrier

    // ---- register-resident JV shortest-augmenting-path (trajectory-exact, f64 duals) ----
    // lane ln owns columns j = ln + 64*s (s=0..4); slot 4 invalid for ln>=44
    const double DINF = __builtin_inf();
    double u = 0.0;                     // dual for row ln (ln<50)
    int c4r = -1;                       // col4row[ln]
    double v[5], sh[5];
    int pth[5], r4c[5];
    #pragma unroll
    for (int s = 0; s < 5; ++s) { v[s] = 0.0; r4c[s] = -1; }

    for (int curRow = 0; curRow < NT; ++curRow) {
        #pragma unroll
        for (int s = 0; s < 5; ++s) { sh[s] = DINF; pth[s] = -1; }
        int SCm = (ln < 44) ? 0 : 0x10;            // invalid slot pre-closed
        unsigned long long SRmask = 0ull;
        int i = curRow;
        double minVal = 0.0;
        int sink = -1;

        while (true) {
            SRmask |= (1ull << i);
            float cf[5];
            #pragma unroll
            for (int s = 0; s < 5; ++s) cf[s] = tile[i*TSTRIDE + ln + 64*s];
            double u_i = readlane_f64(u, i);       // i is wave-uniform -> v_readlane
            #pragma unroll
            for (int s = 0; s < 5; ++s) {
                bool open = ((SCm >> s) & 1) == 0;
                double r = ((minVal + (double)cf[s]) - u_i) - v[s];  // reference op order
                bool upd = open && (r < sh[s]);
                sh[s]  = upd ? r : sh[s];
                pth[s] = upd ? i : pth[s];
            }
            // open-only fold, tree depth 3
            double l0f = (((SCm>>0)&1)==0) ? sh[0] : DINF;
            double l1f = (((SCm>>1)&1)==0) ? sh[1] : DINF;
            double l2f = (((SCm>>2)&1)==0) ? sh[2] : DINF;
            double l3f = (((SCm>>3)&1)==0) ? sh[3] : DINF;
            double l4f = (((SCm>>4)&1)==0) ? sh[4] : DINF;
            double lmin = fmin(fmin(fmin(l0f,l1f), fmin(l2f,l3f)), l4f);

            // f32 pre-reduce (monotone cast); exact when unique candidate lane
            float k32 = (float)lmin;
            float m32 = wave_min_f32(k32);
            unsigned long long candm = __ballot(k32 == m32);
            double m;
            int jstar, rc;
            if (__popcll(candm) == 1) {
                int cl = (int)__builtin_ctzll(candm);
                m = readlane_f64(lmin, cl);        // exact f64 min (cand lane's lmin)
                // per-lane: smallest open s with sh[s]==m, and its row4col
                int smin = 0, rcl = -1;
                #pragma unroll
                for (int s = 4; s >= 0; --s) {
                    bool match = (((SCm >> s) & 1) == 0) && (sh[s] == m);
                    smin = match ? s : smin;
                    rcl  = match ? r4c[s] : rcl;
                }
                jstar = __builtin_amdgcn_readlane(smin, cl) * 64 + cl;
                rc    = __builtin_amdgcn_readlane(rcl, cl);
            } else {
                // exact slow path (handles cross-lane f32 ties; np.argmin order)
                m = wave_min_f64(lmin);
                unsigned long long b0 = __ballot((((SCm >> 0) & 1) == 0) && (sh[0] == m));
                unsigned long long b1 = __ballot((((SCm >> 1) & 1) == 0) && (sh[1] == m));
                unsigned long long b2 = __ballot((((SCm >> 2) & 1) == 0) && (sh[2] == m));
                unsigned long long b3 = __ballot((((SCm >> 3) & 1) == 0) && (sh[3] == m));
                unsigned long long b4 = __ballot((((SCm >> 4) & 1) == 0) && (sh[4] == m));
                if      (b0) jstar =       __builtin_ctzll(b0);
                else if (b1) jstar =  64 + __builtin_ctzll(b1);
                else if (b2) jstar = 128 + __builtin_ctzll(b2);
                else if (b3) jstar = 192 + __builtin_ctzll(b3);
                else         jstar = 256 + __builtin_ctzll(b4);
                unsigned long long mm = __ballot((ln < NT) && (c4r == jstar));
                rc = (mm == 0ull) ? -1 : (int)__builtin_ctzll(mm);
            }
            minVal = m;
            // close column jstar
            if (ln == (jstar & 63)) SCm |= 1 << (jstar >> 6);
            if (rc < 0) { sink = jstar; break; }
            i = rc;
        }

        // ---- dual updates (pre-augment col4row) ----
        int cg  = (c4r >= 0) ? c4r : 0;
        int gow = cg & 63, gsl = cg >> 6;
        double g0 = __shfl(sh[0], gow);
        double g1 = __shfl(sh[1], gow);
        double g2 = __shfl(sh[2], gow);
        double g3 = __shfl(sh[3], gow);
        double g4 = __shfl(sh[4], gow);
        double gg = g0;
        gg = (gsl == 1) ? g1 : gg;
        gg = (gsl == 2) ? g2 : gg;
        gg = (gsl == 3) ? g3 : gg;
        gg = (gsl == 4) ? g4 : gg;
        bool inSR = (ln < NT) && ((SRmask >> ln) & 1ull);
        double du = (ln == curRow) ? minVal : (minVal - gg);
        u = inSR ? (u + du) : u;
        #pragma unroll
        for (int s = 0; s < 5; ++s) {
            bool closed = ((SCm >> s) & 1) != 0;
            v[s] = closed ? (v[s] - (minVal - sh[s])) : v[s];
        }

        // ---- augment (uniform j/i chain -> readlane); maintain r4c mirror ----
        int j = sink;
        while (true) {
            int ow2 = j & 63, sl2 = j >> 6;
            int ps = pth[0];
            ps = (sl2==1) ? pth[1] : ps;
            ps = (sl2==2) ? pth[2] : ps;
            ps = (sl2==3) ? pth[3] : ps;
            ps = (sl2==4) ? pth[4] : ps;
            int ii = __builtin_amdgcn_readlane(ps, ow2);   // path[j]
            #pragma unroll
            for (int s = 0; s < 5; ++s)
                r4c[s] = (ln == ow2 && s == sl2) ? ii : r4c[s];   // row4col[j] = ii
            int jj = __builtin_amdgcn_readlane(c4r, ii);   // old col4row[ii]
            if (ln == ii) c4r = j;                          // col4row[ii] = j
            j = jj;
            if (ii == curRow) break;
        }
    }

    // ---- emit indices (argsort of matched pred indices) ----
    int* smem_i = (int*)smem;                       // tile is dead
    __threadfence_block();
    if (ln < NT) smem_i[ln] = c4r;
    __threadfence_block();
    int myc = c4r;
    int rank = 0;
    for (int s2 = 0; s2 < NT; ++s2) rank += (smem_i[s2] < myc) ? 1 : 0;
    if (ln < NT) {
        out_idx[b*(2*NT) + rank]      = (float)myc; // sorted pred (q) indices
        out_idx[b*(2*NT) + NT + rank] = (float)ln;  // matched tgt (t) indices
    }
}

extern "C" void kernel_launch(void* const* d_in, const int* in_sizes, int n_in,
                              void* d_out, int out_size, void* d_ws, size_t ws_size,
                              hipStream_t stream)
{
    const float* pred_kp    = (const float*)d_in[0];
    const float* pred_boxes = (const float*)d_in[1];
    const float* tgt_boxes  = (const float*)d_in[2];
    const float* tgt_kp     = (const float*)d_in[3];
    float* C   = (float*)d_out;
    float* idx = C + NC;
    // blocks 0..15: per-batch LAP (dispatched first); blocks 16..765: cost matrix
    fused_kernel<<<dim3(BSZ + 750), 1024, 0, stream>>>(
        pred_kp, pred_boxes, tgt_boxes, tgt_kp, C, idx);
}